// Round 12
// baseline (355.650 us; speedup 1.0000x reference)
//
#include <hip/hip_runtime.h>
#include <stdint.h>

#define NN 8192
#define IN_DIM 32
#define HID_DIM 64
#define OUT_DIM 16

typedef __attribute__((ext_vector_type(8))) short short8;
typedef __attribute__((ext_vector_type(4))) float f32x4;

// fp32 -> bf16 bits, round-to-nearest-even
__device__ __forceinline__ short f2bf_bits(float x){
  uint32_t u = __builtin_bit_cast(uint32_t, x);
  u += 0x7FFFu + ((u >> 16) & 1u);
  return (short)(u >> 16);
}

__device__ __forceinline__ short8 cvt8(f32x4 lo, f32x4 hi){
  short8 r;
  r[0]=f2bf_bits(lo[0]); r[1]=f2bf_bits(lo[1]); r[2]=f2bf_bits(lo[2]); r[3]=f2bf_bits(lo[3]);
  r[4]=f2bf_bits(hi[0]); r[5]=f2bf_bits(hi[1]); r[6]=f2bf_bits(hi[2]); r[7]=f2bf_bits(hi[3]);
  return r;
}

// Kernel 0: Gt[c][r] = bf16( (X @ W1)[r][c] )   [64][8192]
__global__ __launch_bounds__(256) void k_g(const float* __restrict__ X, const float* __restrict__ W1,
                                           short* __restrict__ Gt){
  const int b    = blockIdx.x;
  const int rb   = (b & 127) * 64;
  const int cg   = b >> 7;
  const int lane = threadIdx.x & 63;
  const int c    = cg * 4 + (threadIdx.x >> 6);
  const int r    = rb + lane;
  const float* xr = X + (size_t)r * IN_DIM;
  float acc = 0.f;
  #pragma unroll
  for (int k = 0; k < IN_DIM; ++k)
    acc += xr[k] * W1[(size_t)k * HID_DIM + c];
  Gt[(size_t)c * NN + r] = f2bf_bits(acc);
}

// mm64r: R11 structure. REPACK=1 additionally stores the cvt8 bf16 fragments
// to adjh (row-major [8192][8192] bf16) -- free fp32->bf16 repack fused into
// layer 1's mandatory stream. Ledger re-derived with 4 stores/group in the
// in-order vmcnt stream: steady waits 8/12 (non-repack: 4/8); prologue issues
// 4 dummy stores (same addrs compute(0) later overwrites) so static counts
// hold from iteration 0; epilogue 8/12/8/4 (4/8/4/0).
template<int REV, int REPACK>
__global__ __launch_bounds__(64, 2) void mm64r(const float* __restrict__ adj1, const float* __restrict__ adj2,
                                               const short* __restrict__ Bt,
                                               short* __restrict__ adjh1, short* __restrict__ adjh2,
                                               float* __restrict__ P1, float* __restrict__ P2, int klen){
  __shared__ __align__(16) float sA[2][64 * 32];      // 2 x 8 KB ring
  const int l     = threadIdx.x;                      // 0..63
  const int strip = REV ? ((int)gridDim.x - 1 - (int)blockIdx.x) : (int)blockIdx.x;
  const int ks    = REV ? ((int)gridDim.y - 1 - (int)blockIdx.y) : (int)blockIdx.y;
  const int z     = REV ? (1 - (int)blockIdx.z) : (int)blockIdx.z;
  const float* __restrict__ adj = z ? adj2 : adj1;
  short* __restrict__ adjh = z ? adjh2 : adjh1;
  const int k0    = ks * klen;
  const int ngrp  = klen >> 5;                        // 32 at S=8
  const int phase = (strip + (z << 3)) & (ngrp - 1);
  const int rl    = l & 15;
  const int qh    = l >> 4;
  const int sr8   = l >> 3;
  const int sg    = (l & 7) ^ sr8;
  const size_t rowb = (size_t)strip * 64 * NN;

  auto gmap = [&](int t){
    const int tg = REV ? (phase + ngrp - 1 - t) : (phase + t);
    return tg & (ngrp - 1);
  };

  auto SL = [&](int t, f32x4 (&R)[8]){
    const int g = gmap(t);
    const float* base = adj + rowb + (size_t)(k0 + g * 32) + sg * 4;
    #pragma unroll
    for (int p = 0; p < 8; ++p)
      R[p] = *(const f32x4*)(base + (size_t)(p * 8 + sr8) * NN);
  };

  auto DW = [&](const f32x4 (&R)[8], float* buf){
    float* dst = buf + (l & 7) * 4;
    #pragma unroll
    for (int p = 0; p < 8; ++p)
      *(f32x4*)(dst + (p * 8 + sr8) * 32) = R[p];
  };

  auto BL = [&](int t, short8 (&d)[4]){
    const int g = gmap(t);
    const size_t bk = (size_t)(k0 + g * 32) + qh * 8;
    #pragma unroll
    for (int f = 0; f < 4; ++f)
      d[f] = *(const short8*)(Bt + (size_t)(f * 16 + rl) * NN + bk);
  };

  f32x4 acc[4][4];
  #pragma unroll
  for (int mi = 0; mi < 4; ++mi)
    #pragma unroll
    for (int f = 0; f < 4; ++f)
      acc[mi][f] = f32x4{0.f,0.f,0.f,0.f};

  auto compute = [&](int g, const float* sa, const short8 (&b)[4]){
    #pragma unroll
    for (int mi = 0; mi < 4; ++mi){
      const int row = mi * 16 + rl;
      f32x4 lo = *(const f32x4*)(sa + row * 32 + (((qh * 2    ) ^ (rl & 7)) << 2));
      f32x4 hi = *(const f32x4*)(sa + row * 32 + (((qh * 2 + 1) ^ (rl & 7)) << 2));
      short8 fa = cvt8(lo, hi);
      if constexpr (REPACK)
        *(short8*)(adjh + (size_t)(strip * 64 + mi * 16 + rl) * NN + (k0 + g * 32 + qh * 8)) = fa;
      #pragma unroll
      for (int f = 0; f < 4; ++f)
        acc[mi][f] = __builtin_amdgcn_mfma_f32_16x16x32_bf16(fa, b[f], acc[mi][f], 0, 0, 0);
    }
  };

  f32x4 SA[8];
  short8 bA[4], bB[4];

  SL(0, SA); BL(0, bA);
  if constexpr (REPACK){
    // dummy stores at compute(0)'s addresses: keep the static ledger exact
    const int g0 = gmap(0);
    const short8 zz = {0,0,0,0,0,0,0,0};
    #pragma unroll
    for (int mi = 0; mi < 4; ++mi)
      *(short8*)(adjh + (size_t)(strip * 64 + mi * 16 + rl) * NN + (k0 + g0 * 32 + qh * 8)) = zz;
  }

  #define WAIT_A do{ if constexpr (REPACK) asm volatile("s_waitcnt vmcnt(8)" ::: "memory"); \
                     else asm volatile("s_waitcnt vmcnt(4)" ::: "memory"); \
                     __builtin_amdgcn_sched_barrier(0); }while(0)
  #define WAIT_B do{ if constexpr (REPACK) asm volatile("s_waitcnt vmcnt(12)" ::: "memory"); \
                     else asm volatile("s_waitcnt vmcnt(8)" ::: "memory"); \
                     __builtin_amdgcn_sched_barrier(0); }while(0)

  #pragma unroll 1
  for (int t = 0; t < ngrp - 2; t += 2){
    WAIT_A;                                           // SL(t) arrived
    DW(SA, &sA[0][0]);
    SL(t + 1, SA);
    WAIT_B;                                           // BL(t) arrived
    BL(t + 1, bB);
    compute(gmap(t), &sA[0][0], bA);
    WAIT_A;                                           // SL(t+1) arrived
    DW(SA, &sA[1][0]);
    SL(t + 2, SA);
    WAIT_B;                                           // BL(t+1) arrived
    BL(t + 2, bA);
    compute(gmap(t + 1), &sA[1][0], bB);
  }
  // epilogue: groups ngrp-2, ngrp-1
  WAIT_A;
  DW(SA, &sA[0][0]);
  SL(ngrp - 1, SA);
  WAIT_B;
  BL(ngrp - 1, bB);
  compute(gmap(ngrp - 2), &sA[0][0], bA);
  WAIT_A;                                             // SL(ngrp-1) arrived
  DW(SA, &sA[1][0]);
  if constexpr (REPACK) asm volatile("s_waitcnt vmcnt(4)" ::: "memory");
  else                  asm volatile("s_waitcnt vmcnt(0)" ::: "memory");
  __builtin_amdgcn_sched_barrier(0);
  compute(gmap(ngrp - 1), &sA[1][0], bB);
  #undef WAIT_A
  #undef WAIT_B

  float* P = z ? P2 : P1;
  #pragma unroll
  for (int mi = 0; mi < 4; ++mi){
    const int orow = strip * 64 + mi * 16 + qh * 4;
    float* p = P + ((size_t)ks * NN + orow) * HID_DIM + rl;
    #pragma unroll
    for (int r = 0; r < 4; ++r){
      #pragma unroll
      for (int f = 0; f < 4; ++f)
        p[(size_t)r * HID_DIM + f * 16] = acc[mi][f][r];
    }
  }
}

// mm2h: layer-2 mm on bf16 adjh (half bytes, half line-requests). Single-wave
// block, 64 rows of one matrix; K-group=64 (128 B/row); gload_lds staging into
// ring-2 8 KB (10 blocks/CU); single counted vmcnt(16) per group; skew + REV
// temporal mirror (adjh is L3-hot: mm1 just wrote it).
template<int REV>
__global__ __launch_bounds__(64, 2) void mm2h(const short* __restrict__ A1, const short* __restrict__ A2,
                                              const short* __restrict__ Bt,
                                              float* __restrict__ P1, float* __restrict__ P2, int klen){
  __shared__ __align__(16) short hA[2][64 * 64];      // 2 x 8 KB
  const int l     = threadIdx.x;
  const int strip = REV ? ((int)gridDim.x - 1 - (int)blockIdx.x) : (int)blockIdx.x;
  const int ks    = REV ? ((int)gridDim.y - 1 - (int)blockIdx.y) : (int)blockIdx.y;
  const int z     = REV ? (1 - (int)blockIdx.z) : (int)blockIdx.z;
  const short* __restrict__ A = z ? A2 : A1;
  const int k0    = ks * klen;
  const int ngrp  = klen >> 6;                        // 16 at S=8
  const int phase = (strip + (z << 3)) & (ngrp - 1);
  const int rl    = l & 15;
  const int qh    = l >> 4;
  const int sr    = l >> 3;                           // stage row-in-8 = swizzle key
  const int sgr   = (l & 7) ^ sr;                     // source granule (16B = 8 bf16)
  const size_t rowb = (size_t)strip * 64 * NN;

  auto gmap = [&](int t){
    const int tg = REV ? (phase + ngrp - 1 - t) : (phase + t);
    return tg & (ngrp - 1);
  };

  auto SL = [&](int t, int buf){
    const int g = gmap(t);
    const size_t colb = (size_t)(k0 + g * 64);
    #pragma unroll
    for (int p = 0; p < 8; ++p){
      const int row = p * 8 + sr;                     // 0..63; row&7 == sr
      const short* s = A + rowb + (size_t)row * NN + colb + sgr * 8;
      __builtin_amdgcn_global_load_lds(
          (const __attribute__((address_space(1))) void*)s,
          (__attribute__((address_space(3))) void*)&hA[buf][p * 512 + l * 8], 16, 0, 0);
    }
  };

  auto BL = [&](int t, short8 (&d)[2][4]){
    const int g = gmap(t);
    const size_t bk = (size_t)(k0 + g * 64) + qh * 8;
    #pragma unroll
    for (int j = 0; j < 2; ++j)
      #pragma unroll
      for (int f = 0; f < 4; ++f)
        d[j][f] = *(const short8*)(Bt + (size_t)(f * 16 + rl) * NN + bk + j * 32);
  };

  f32x4 acc[4][4];
  #pragma unroll
  for (int mi = 0; mi < 4; ++mi)
    #pragma unroll
    for (int f = 0; f < 4; ++f)
      acc[mi][f] = f32x4{0.f,0.f,0.f,0.f};

  auto compute = [&](const short* sa, const short8 (&b)[2][4]){
    #pragma unroll
    for (int j = 0; j < 2; ++j){
      #pragma unroll
      for (int mi = 0; mi < 4; ++mi){
        const int row = mi * 16 + rl;
        const int c   = j * 4 + qh;                   // granule 0..7
        short8 fa = *(const short8*)(sa + row * 64 + ((c ^ (row & 7)) << 3));
        #pragma unroll
        for (int f = 0; f < 4; ++f)
          acc[mi][f] = __builtin_amdgcn_mfma_f32_16x16x32_bf16(fa, b[j][f], acc[mi][f], 0, 0, 0);
      }
    }
  };

  short8 bA[2][4], bB[2][4];

  BL(0, bA); SL(0, 0);

  #pragma unroll 1
  for (int t = 0; t < ngrp - 2; t += 2){
    BL(t + 1, bB); SL(t + 1, 1);
    asm volatile("s_waitcnt vmcnt(16)" ::: "memory"); // retires through SL(t) (+BL(t), older)
    __builtin_amdgcn_sched_barrier(0);
    compute(&hA[0][0], bA);
    BL(t + 2, bA); SL(t + 2, 0);
    asm volatile("s_waitcnt vmcnt(16)" ::: "memory"); // retires through SL(t+1)
    __builtin_amdgcn_sched_barrier(0);
    compute(&hA[1][0], bB);
  }
  // epilogue: groups ngrp-2 (buf0), ngrp-1 (buf1)
  BL(ngrp - 1, bB); SL(ngrp - 1, 1);
  asm volatile("s_waitcnt vmcnt(16)" ::: "memory");
  __builtin_amdgcn_sched_barrier(0);
  compute(&hA[0][0], bA);
  asm volatile("s_waitcnt vmcnt(0)" ::: "memory");
  __builtin_amdgcn_sched_barrier(0);
  compute(&hA[1][0], bB);

  float* P = z ? P2 : P1;
  #pragma unroll
  for (int mi = 0; mi < 4; ++mi){
    const int orow = strip * 64 + mi * 16 + qh * 4;
    float* p = P + ((size_t)ks * NN + orow) * HID_DIM + rl;
    #pragma unroll
    for (int r = 0; r < 4; ++r){
      #pragma unroll
      for (int f = 0; f < 4; ++f)
        p[(size_t)r * HID_DIM + f * 16] = acc[mi][f][r];
    }
  }
}

// l1_combine: H1t[c][r] = bf16( relu(SY1+b1) + relu(SY2+b1) ), LDS transpose
__global__ __launch_bounds__(256) void l1_combine(const float* __restrict__ Y1p, const float* __restrict__ Y2p,
                                                  const float* __restrict__ b1,
                                                  short* __restrict__ H1t, int S){
  __shared__ float sH[64][65];
  const int tid = threadIdx.x, lane = tid & 63, wave = tid >> 6;
  const int rb = blockIdx.x * 64;
  const float bc = b1[lane];
  #pragma unroll 4
  for (int rq = 0; rq < 16; ++rq){
    const int r = rq * 4 + wave;
    const int row = rb + r;
    float s1 = 0.f, s2 = 0.f;
    for (int sp = 0; sp < S; ++sp){
      s1 += Y1p[((size_t)sp * NN + row) * HID_DIM + lane];
      s2 += Y2p[((size_t)sp * NN + row) * HID_DIM + lane];
    }
    sH[r][lane] = fmaxf(s1 + bc, 0.f) + fmaxf(s2 + bc, 0.f);
  }
  __syncthreads();
  #pragma unroll 4
  for (int i = 0; i < 16; ++i){
    const int c = wave * 16 + i;
    H1t[(size_t)c * NN + rb + lane] = f2bf_bits(sH[lane][c]);
  }
}

// l2_combine: out[row][c] = relu(Z1@W2+b2) + relu(Z2@W2+b2)
__global__ __launch_bounds__(256) void l2_combine(const float* __restrict__ Z1p, const float* __restrict__ Z2p,
                                                  const float* __restrict__ W2, const float* __restrict__ b2,
                                                  float* __restrict__ out, int S){
  __shared__ float sW[HID_DIM * OUT_DIM];
  __shared__ float sb[OUT_DIM];
  __shared__ float sz[4][2][HID_DIM];
  const int tid = threadIdx.x;
  for (int i = tid; i < HID_DIM * OUT_DIM; i += 256) sW[i] = W2[i];
  if (tid < OUT_DIM) sb[tid] = b2[tid];
  const int sub = tid >> 6, t = tid & 63;
  const int row = blockIdx.x * 4 + sub;
  float s1 = 0.f, s2 = 0.f;
  for (int sp = 0; sp < S; ++sp){
    s1 += Z1p[((size_t)sp * NN + row) * HID_DIM + t];
    s2 += Z2p[((size_t)sp * NN + row) * HID_DIM + t];
  }
  sz[sub][0][t] = s1;
  sz[sub][1][t] = s2;
  __syncthreads();
  if (t < OUT_DIM){
    float a = sb[t], b = sb[t];
    #pragma unroll
    for (int k = 0; k < HID_DIM; ++k){
      a += sz[sub][0][k] * sW[k * OUT_DIM + t];
      b += sz[sub][1][k] * sW[k * OUT_DIM + t];
    }
    out[(size_t)row * OUT_DIM + t] = fmaxf(a, 0.f) + fmaxf(b, 0.f);
  }
}

extern "C" void kernel_launch(void* const* d_in, const int* in_sizes, int n_in,
                              void* d_out, int out_size, void* d_ws, size_t ws_size,
                              hipStream_t stream){
  const float* adj1 = (const float*)d_in[0];
  const float* adj2 = (const float*)d_in[1];
  const float* X    = (const float*)d_in[2];
  const float* W1   = (const float*)d_in[3];
  const float* b1   = (const float*)d_in[4];
  const float* W2   = (const float*)d_in[5];
  const float* b2   = (const float*)d_in[6];
  float* out = (float*)d_out;

  const size_t MB = 1024 * 1024;
  char* ws = (char*)d_ws;
  short* Gt  = (short*)ws;                            // 1 MB
  short* H1t = (short*)(ws + 1 * MB);                 // 1 MB

  if (ws_size >= 291 * MB){
    // repack path: S=8 fixed. P: 2MB..34MB; adjh: 34MB..290MB
    const int S = 8, klen = NN / 8;
    float* P1 = (float*)(ws + 2 * MB);
    float* P2 = P1 + (size_t)S * NN * HID_DIM;        // 16 MB each
    short* adjh1 = (short*)(ws + 34 * MB);            // 128 MB
    short* adjh2 = (short*)(ws + 162 * MB);           // 128 MB

    k_g         <<<dim3(2048),          dim3(256), 0, stream>>>(X, W1, Gt);
    mm64r<0, 1> <<<dim3(NN / 64, S, 2), dim3(64),  0, stream>>>(adj1, adj2, Gt, adjh1, adjh2, P1, P2, klen);
    l1_combine  <<<dim3(NN / 64),       dim3(256), 0, stream>>>(P1, P2, b1, H1t, S);
    mm2h<1>     <<<dim3(NN / 64, S, 2), dim3(64),  0, stream>>>(adjh1, adjh2, H1t, P1, P2, klen);
    l2_combine  <<<dim3(NN / 4),        dim3(256), 0, stream>>>(P1, P2, W2, b2, out, S);
  } else {
    // fallback: R11 path verbatim (fp32 both layers)
    int S = 8;
    const size_t off = 2 * MB;
    while (S > 1 && off + (size_t)S * 4 * MB > ws_size) S >>= 1;
    float* P1 = (float*)(ws + off);
    float* P2 = P1 + (size_t)S * NN * HID_DIM;
    const int klen = NN / S;

    k_g         <<<dim3(2048),          dim3(256), 0, stream>>>(X, W1, Gt);
    mm64r<0, 0> <<<dim3(NN / 64, S, 2), dim3(64),  0, stream>>>(adj1, adj2, Gt, nullptr, nullptr, P1, P2, klen);
    l1_combine  <<<dim3(NN / 64),       dim3(256), 0, stream>>>(P1, P2, b1, H1t, S);
    mm64r<1, 0> <<<dim3(NN / 64, S, 2), dim3(64),  0, stream>>>(adj1, adj2, H1t, nullptr, nullptr, P1, P2, klen);
    l2_combine  <<<dim3(NN / 4),        dim3(256), 0, stream>>>(P1, P2, W2, b2, out, S);
  }
}

// Round 13
// 294.234 us; speedup vs baseline: 1.2087x; 1.2087x over previous
//
#include <hip/hip_runtime.h>
#include <stdint.h>

#define NN 8192
#define IN_DIM 32
#define HID_DIM 64
#define OUT_DIM 16

typedef __attribute__((ext_vector_type(8))) short short8;
typedef __attribute__((ext_vector_type(4))) float f32x4;

// fp32 -> bf16 bits, round-to-nearest-even
__device__ __forceinline__ short f2bf_bits(float x){
  uint32_t u = __builtin_bit_cast(uint32_t, x);
  u += 0x7FFFu + ((u >> 16) & 1u);
  return (short)(u >> 16);
}

__device__ __forceinline__ short8 cvt8(f32x4 lo, f32x4 hi){
  short8 r;
  r[0]=f2bf_bits(lo[0]); r[1]=f2bf_bits(lo[1]); r[2]=f2bf_bits(lo[2]); r[3]=f2bf_bits(lo[3]);
  r[4]=f2bf_bits(hi[0]); r[5]=f2bf_bits(hi[1]); r[6]=f2bf_bits(hi[2]); r[7]=f2bf_bits(hi[3]);
  return r;
}

// Kernel 0: Gt[c][r] = bf16( (X @ W1)[r][c] )   [64][8192]
__global__ __launch_bounds__(256) void k_g(const float* __restrict__ X, const float* __restrict__ W1,
                                           short* __restrict__ Gt){
  const int b    = blockIdx.x;
  const int rb   = (b & 127) * 64;
  const int cg   = b >> 7;
  const int lane = threadIdx.x & 63;
  const int c    = cg * 4 + (threadIdx.x >> 6);
  const int r    = rb + lane;
  const float* xr = X + (size_t)r * IN_DIM;
  float acc = 0.f;
  #pragma unroll
  for (int k = 0; k < IN_DIM; ++k)
    acc += xr[k] * W1[(size_t)k * HID_DIM + c];
  Gt[(size_t)c * NN + r] = f2bf_bits(acc);
}

// mm32: single-wave block, M=32 rows of ONE adj matrix, K-group = 128 cols
// = 512 B CONTIGUOUS per row-visit (4 cache lines per DRAM page activate;
// R12 established the machine pins at ~24G 128B-visits/s -> amortize the
// activate over 4x the bytes). R11 skeleton otherwise verbatim: no barriers,
// named double-buffers (bA/bB + LDS buf0/buf1), static vmcnt ledger
// (32 ops/group: 16 gload_lds A + 16 reg-load B), skew, REV temporal mirror.
// LDS 2x16 KB -> 5 blocks/CU. XOR swizzle at global source, LDS linear:
// slot s of row r holds source granule s^(r&7); reads undo it (2-way max).
template<int REV>
__global__ __launch_bounds__(64, 2) void mm32(const float* __restrict__ adj1, const float* __restrict__ adj2,
                                              const short* __restrict__ Bt,
                                              float* __restrict__ P1, float* __restrict__ P2, int klen){
  __shared__ __align__(16) float sA[2][32 * 128];     // 2 x 16 KB
  const int l     = threadIdx.x;                      // 0..63
  const int strip = REV ? ((int)gridDim.x - 1 - (int)blockIdx.x) : (int)blockIdx.x;
  const int ks    = REV ? ((int)gridDim.y - 1 - (int)blockIdx.y) : (int)blockIdx.y;
  const int z     = REV ? (1 - (int)blockIdx.z) : (int)blockIdx.z;
  const float* __restrict__ adj = z ? adj2 : adj1;
  const int k0    = ks * klen;
  const int ngrp  = klen >> 7;                        // 8 at S=8
  const int phase = (strip + (z << 2)) & (ngrp - 1);  // channel-spread skew
  const int rl    = l & 15;                           // MFMA row / B col
  const int qh    = l >> 4;                           // k-quad
  const int shi   = l >> 5;                           // stage row parity
  const int sgr   = l & 31;                           // stage granule slot
  const size_t rowb = (size_t)strip * 32 * NN;

  auto gmap = [&](int t){
    const int tg = REV ? (phase + ngrp - 1 - t) : (phase + t);
    return tg & (ngrp - 1);
  };

  // stage group t: 16 instrs, each 1 KB linear LDS = rows 2p,2p+1 x 512 B
  auto SL = [&](int t, int buf){
    const int g = gmap(t);
    const size_t colb = (size_t)(k0 + g * 128);
    #pragma unroll
    for (int p = 0; p < 16; ++p){
      const int row = p * 2 + shi;                    // 0..31
      const int gs  = sgr ^ (row & 7);                // swizzled source granule
      const float* s = adj + rowb + (size_t)row * NN + colb + gs * 4;
      __builtin_amdgcn_global_load_lds(
          (const __attribute__((address_space(1))) void*)s,
          (__attribute__((address_space(3))) void*)&sA[buf][p * 256 + l * 4], 16, 0, 0);
    }
  };

  auto BL = [&](int t, short8 (&d)[4][4]){            // [j][f], L2-resident Gt
    const int g = gmap(t);
    const size_t bk = (size_t)(k0 + g * 128) + qh * 8;
    #pragma unroll
    for (int j = 0; j < 4; ++j)
      #pragma unroll
      for (int f = 0; f < 4; ++f)
        d[j][f] = *(const short8*)(Bt + (size_t)(f * 16 + rl) * NN + bk + j * 32);
  };

  f32x4 acc[2][4];
  #pragma unroll
  for (int mi = 0; mi < 2; ++mi)
    #pragma unroll
    for (int f = 0; f < 4; ++f)
      acc[mi][f] = f32x4{0.f,0.f,0.f,0.f};

  auto compute = [&](int buf, const short8 (&b)[4][4]){
    const float* sa = &sA[buf][0];
    #pragma unroll
    for (int j = 0; j < 4; ++j){
      const int g0 = j * 8 + qh * 2;
      #pragma unroll
      for (int mi = 0; mi < 2; ++mi){
        const int r    = mi * 16 + rl;
        const int base = (r >> 1) * 256 + (r & 1) * 128;
        f32x4 lo = *(const f32x4*)(sa + base + (((g0    ) ^ (r & 7)) << 2));
        f32x4 hi = *(const f32x4*)(sa + base + (((g0 + 1) ^ (r & 7)) << 2));
        short8 fa = cvt8(lo, hi);
        #pragma unroll
        for (int f = 0; f < 4; ++f)
          acc[mi][f] = __builtin_amdgcn_mfma_f32_16x16x32_bf16(fa, b[j][f], acc[mi][f], 0, 0, 0);
      }
    }
  };

  short8 bA[4][4], bB[4][4];

  // prologue: groups 0,1 fully issued (64 ops outstanding; waits use value 32)
  BL(0, bA); SL(0, 0);
  BL(1, bB); SL(1, 1);

  #pragma unroll 1
  for (int t = 0; t < ngrp - 2; t += 2){
    asm volatile("s_waitcnt vmcnt(32)" ::: "memory"); // group t done (t+1 in flight)
    __builtin_amdgcn_sched_barrier(0);
    compute(0, bA);
    BL(t + 2, bA); SL(t + 2, 0);                      // refill after consume
    asm volatile("s_waitcnt vmcnt(32)" ::: "memory"); // group t+1 done
    __builtin_amdgcn_sched_barrier(0);
    compute(1, bB);
    BL(t + 3, bB); SL(t + 3, 1);
  }
  asm volatile("s_waitcnt vmcnt(32)" ::: "memory");   // group ngrp-2 done
  __builtin_amdgcn_sched_barrier(0);
  compute(0, bA);
  asm volatile("s_waitcnt vmcnt(0)" ::: "memory");    // group ngrp-1 done
  __builtin_amdgcn_sched_barrier(0);
  compute(1, bB);

  // D layout per 16x16 frag: col = lane&15, row = (lane>>4)*4 + reg
  float* P = z ? P2 : P1;
  #pragma unroll
  for (int mi = 0; mi < 2; ++mi){
    const int orow = strip * 32 + mi * 16 + qh * 4;
    float* p = P + ((size_t)ks * NN + orow) * HID_DIM + rl;
    #pragma unroll
    for (int r = 0; r < 4; ++r){
      #pragma unroll
      for (int f = 0; f < 4; ++f)
        p[(size_t)r * HID_DIM + f * 16] = acc[mi][f][r];
    }
  }
}

// l1_combine: H1t[c][r] = bf16( relu(SY1+b1) + relu(SY2+b1) ), LDS transpose
__global__ __launch_bounds__(256) void l1_combine(const float* __restrict__ Y1p, const float* __restrict__ Y2p,
                                                  const float* __restrict__ b1,
                                                  short* __restrict__ H1t, int S){
  __shared__ float sH[64][65];
  const int tid = threadIdx.x, lane = tid & 63, wave = tid >> 6;
  const int rb = blockIdx.x * 64;
  const float bc = b1[lane];
  #pragma unroll 4
  for (int rq = 0; rq < 16; ++rq){
    const int r = rq * 4 + wave;
    const int row = rb + r;
    float s1 = 0.f, s2 = 0.f;
    for (int sp = 0; sp < S; ++sp){
      s1 += Y1p[((size_t)sp * NN + row) * HID_DIM + lane];
      s2 += Y2p[((size_t)sp * NN + row) * HID_DIM + lane];
    }
    sH[r][lane] = fmaxf(s1 + bc, 0.f) + fmaxf(s2 + bc, 0.f);
  }
  __syncthreads();
  #pragma unroll 4
  for (int i = 0; i < 16; ++i){
    const int c = wave * 16 + i;
    H1t[(size_t)c * NN + rb + lane] = f2bf_bits(sH[lane][c]);
  }
}

// l2_combine: out[row][c] = relu(Z1@W2+b2) + relu(Z2@W2+b2)
__global__ __launch_bounds__(256) void l2_combine(const float* __restrict__ Z1p, const float* __restrict__ Z2p,
                                                  const float* __restrict__ W2, const float* __restrict__ b2,
                                                  float* __restrict__ out, int S){
  __shared__ float sW[HID_DIM * OUT_DIM];
  __shared__ float sb[OUT_DIM];
  __shared__ float sz[4][2][HID_DIM];
  const int tid = threadIdx.x;
  for (int i = tid; i < HID_DIM * OUT_DIM; i += 256) sW[i] = W2[i];
  if (tid < OUT_DIM) sb[tid] = b2[tid];
  const int sub = tid >> 6, t = tid & 63;
  const int row = blockIdx.x * 4 + sub;
  float s1 = 0.f, s2 = 0.f;
  for (int sp = 0; sp < S; ++sp){
    s1 += Z1p[((size_t)sp * NN + row) * HID_DIM + t];
    s2 += Z2p[((size_t)sp * NN + row) * HID_DIM + t];
  }
  sz[sub][0][t] = s1;
  sz[sub][1][t] = s2;
  __syncthreads();
  if (t < OUT_DIM){
    float a = sb[t], b = sb[t];
    #pragma unroll
    for (int k = 0; k < HID_DIM; ++k){
      a += sz[sub][0][k] * sW[k * OUT_DIM + t];
      b += sz[sub][1][k] * sW[k * OUT_DIM + t];
    }
    out[(size_t)row * OUT_DIM + t] = fmaxf(a, 0.f) + fmaxf(b, 0.f);
  }
}

extern "C" void kernel_launch(void* const* d_in, const int* in_sizes, int n_in,
                              void* d_out, int out_size, void* d_ws, size_t ws_size,
                              hipStream_t stream){
  const float* adj1 = (const float*)d_in[0];
  const float* adj2 = (const float*)d_in[1];
  const float* X    = (const float*)d_in[2];
  const float* W1   = (const float*)d_in[3];
  const float* b1   = (const float*)d_in[4];
  const float* W2   = (const float*)d_in[5];
  const float* b2   = (const float*)d_in[6];
  float* out = (float*)d_out;

  const size_t MB = 1024 * 1024;
  char* ws = (char*)d_ws;
  short* Gt  = (short*)ws;                            // 1 MB
  short* H1t = (short*)(ws + 1 * MB);                 // 1 MB
  const size_t off = 2 * MB;

  int S = 8;
  while (S > 1 && off + (size_t)S * 4 * MB > ws_size) S >>= 1;
  float* P1 = (float*)(ws + off);
  float* P2 = P1 + (size_t)S * NN * HID_DIM;
  const int klen = NN / S;                            // ngrp = klen/128 >= 8

  k_g        <<<dim3(2048),          dim3(256), 0, stream>>>(X, W1, Gt);
  mm32<0>    <<<dim3(NN / 32, S, 2), dim3(64),  0, stream>>>(adj1, adj2, Gt, P1, P2, klen);
  l1_combine <<<dim3(NN / 64),       dim3(256), 0, stream>>>(P1, P2, b1, H1t, S);
  mm32<1>    <<<dim3(NN / 32, S, 2), dim3(64),  0, stream>>>(adj1, adj2, H1t, P1, P2, klen);
  l2_combine <<<dim3(NN / 4),        dim3(256), 0, stream>>>(P1, P2, W2, b2, out, S);
}